// Round 12
// baseline (291.173 us; speedup 1.0000x reference)
//
#include <hip/hip_runtime.h>
#include <hip/hip_bf16.h>

#define NDIM 2048
#define BS   64
#define NM4  (NDIM * NDIM / 4)
#define BSN  ((size_t)BS * NDIM)
#define ZSTRIDE ((size_t)4 * BSN + 2048)   // 4-chain z slab + 4KB pad
#define SMEM_BYTES 71680   // wgemm: 4x16KB A+B pipeline (+34.8KB tileT reuse); skinny: 64+4+2KB

typedef __bf16 bf16_t;
typedef __bf16 bf16x4 __attribute__((ext_vector_type(4)));
typedef __bf16 bf16x8 __attribute__((ext_vector_type(8)));
typedef float  f32x4  __attribute__((ext_vector_type(4)));
typedef unsigned long long u64_t;

// Async global->LDS, 16 B per lane.  LDS dest = wave-uniform base + lane*16.
__device__ __forceinline__ void gload16(const void* g, void* lds) {
  __builtin_amdgcn_global_load_lds(
      (const __attribute__((address_space(1))) void*)g,
      (__attribute__((address_space(3))) void*)lds, 16, 0, 0);
}
// 32-bit LDS byte offset of a generic pointer into __shared__.
__device__ __forceinline__ uint32_t lds_off(void* p) {
  return (uint32_t)(uintptr_t)(__attribute__((address_space(3))) void*)p;
}

// ---------------------------------------------------------------------------
// prep (512 thr, 3072 blocks): b<1024 convert H,U (+y, traj0); else 64x64
// fp32->bf16 vectorized transposes of Dinv, invM.
// ---------------------------------------------------------------------------
__global__ __launch_bounds__(512) void prep(
    const float* __restrict__ H, const float* __restrict__ U,
    const float* __restrict__ Dinv, const float* __restrict__ invM,
    const float* __restrict__ y,
    bf16_t* __restrict__ H16, bf16_t* __restrict__ U16,
    bf16_t* __restrict__ Dt, bf16_t* __restrict__ iMt,
    bf16_t* __restrict__ y16, float* __restrict__ traj0) {
  __shared__ bf16_t tile[64][72];
  int b = blockIdx.x, tid = threadIdx.x;
  if (b < 1024) {
#pragma unroll
    for (int i = 0; i < 4; ++i) {
      int idx = b * 2048 + i * 512 + tid;
      const float* src = (idx < NM4) ? H : U;
      bf16_t* dst = (idx < NM4) ? H16 : U16;
      int j = (idx < NM4) ? idx : idx - NM4;
      float4 v = ((const float4*)src)[j];
      bf16x4 o = {(bf16_t)v.x, (bf16_t)v.y, (bf16_t)v.z, (bf16_t)v.w};
      ((bf16x4*)dst)[j] = o;
    }
    int yi = b * 512 + tid;
    if (yi < BS * NDIM / 4) {
      float4 w = ((const float4*)y)[yi];
      bf16x4 o2 = {(bf16_t)w.x, (bf16_t)w.y, (bf16_t)w.z, (bf16_t)w.w};
      ((bf16x4*)y16)[yi] = o2;
      ((float4*)traj0)[yi] = make_float4(0.f, 0.f, 0.f, 0.f);
    }
  } else {
    int id = b - 1024;
    const float* src = (id < 1024) ? Dinv : invM;
    bf16_t* dst = (id < 1024) ? Dt : iMt;
    id &= 1023;
    int bx = id & 31, by = id >> 5;
    int r = tid >> 3, c8 = (tid & 7) * 8;
    const float* sp = src + (size_t)(by * 64 + r) * NDIM + bx * 64 + c8;
    float4 v0 = *(const float4*)sp;
    float4 v1 = *(const float4*)(sp + 4);
    bf16_t* t = &tile[r][c8];
    t[0] = (bf16_t)v0.x; t[1] = (bf16_t)v0.y; t[2] = (bf16_t)v0.z; t[3] = (bf16_t)v0.w;
    t[4] = (bf16_t)v1.x; t[5] = (bf16_t)v1.y; t[6] = (bf16_t)v1.z; t[7] = (bf16_t)v1.w;
    __syncthreads();
    bf16x8 o;
#pragma unroll
    for (int j = 0; j < 8; ++j) o[j] = tile[c8 + j][r];
    *(bf16x8*)(dst + (size_t)(bx * 64 + r) * NDIM + by * 64 + c8) = o;
  }
}

// ---------------------------------------------------------------------------
// wgemm v9 (VERBATIM from round 9 -- proven 284us ship): reg-staged producer
// + XOR-swizzled conflict-free LDS, 128x128 tile, BK=32, 64 chunks, 4-stage.
// (r10's BK=64 rewrite ICE'd clang; reverted.  One structural change/round.)
// ---------------------------------------------------------------------------
__device__ __forceinline__ void wgemm_role(
    const bf16_t* __restrict__ A, const bf16_t* __restrict__ Bt,
    bf16_t* __restrict__ C, bf16_t* __restrict__ Ct, int blk, char* smem) {
  int tid = threadIdx.x, lane = tid & 63, wave = tid >> 6;
  int xcd = blk & 7, jj = blk >> 3;
  int m0 = (((xcd >> 1) << 2) + (jj >> 3)) * 128;
  int n0 = (((xcd & 1) << 3) + (jj & 7)) * 128;
  int rl = lane & 15, q = lane >> 4;

  if (wave >= 4) {
    // ---- producer: coalesced reg loads, swizzled conflict-free ds_write ---
    int pw = wave - 4;
    int prow = lane >> 2, pkg = lane & 3;      // 4-lane 64B runs
    const bf16_t* PA0 = A  + (size_t)(m0 + pw * 32 + prow) * NDIM + pkg * 8;
    const bf16_t* PA1 = PA0 + 16 * NDIM;
    const bf16_t* PB0 = Bt + (size_t)(n0 + pw * 32 + prow) * NDIM + pkg * 8;
    const bf16_t* PB1 = PB0 + 16 * NDIM;
    char* WA = smem + pw * 2048 + (pkg * 256 + ((prow ^ (pkg * 2)) * 16));

    bf16x8 rE[4], rO[4];
#define PLOAD(R, s)                                  \
    {                                                \
      int _k = (s) * 32;                             \
      R[0] = *(const bf16x8*)(PA0 + _k);             \
      R[1] = *(const bf16x8*)(PA1 + _k);             \
      R[2] = *(const bf16x8*)(PB0 + _k);             \
      R[3] = *(const bf16x8*)(PB1 + _k);             \
    }
#define PWRITE(R, BUF)                               \
    {                                                \
      char* _w = WA + (BUF) * 16384;                 \
      *(bf16x8*)(_w)        = R[0];                  \
      *(bf16x8*)(_w + 1024) = R[1];                  \
      *(bf16x8*)(_w + 8192) = R[2];                  \
      *(bf16x8*)(_w + 9216) = R[3];                  \
    }
#define PITER(R, BUF, kk)                                              \
    {                                                                  \
      asm volatile("s_waitcnt lgkmcnt(0)\n\ts_barrier" ::: "memory");  \
      PWRITE(R, BUF);                                                  \
      PLOAD(R, (kk) + 4);                                              \
    }
    PLOAD(rE, 0); PLOAD(rO, 1);
    PWRITE(rE, 0); PLOAD(rE, 2);
    PWRITE(rO, 1); PLOAD(rO, 3);
#pragma unroll 1
    for (int k = 0; k < 60; k += 4) {
      PITER(rE, 2, k);         // write stage k+2 -> buf 2
      PITER(rO, 3, k + 1);
      PITER(rE, 0, k + 2);
      PITER(rO, 1, k + 3);
    }
    asm volatile("s_waitcnt lgkmcnt(0)\n\ts_barrier" ::: "memory");  // chunk 60
    PWRITE(rE, 2);                                                   // stage 62
    asm volatile("s_waitcnt lgkmcnt(0)\n\ts_barrier" ::: "memory");  // chunk 61
    PWRITE(rO, 3);                                                   // stage 63
    asm volatile("s_waitcnt lgkmcnt(0)\n\ts_barrier" ::: "memory");  // chunk 62
    asm volatile("s_barrier" ::: "memory");                          // chunk 63
#undef PITER
#undef PWRITE
#undef PLOAD
    if (Ct) {
      __syncthreads();   // consumers writing tileT
      __syncthreads();
      bf16_t (*tileT)[136] = (bf16_t(*)[136])smem;
#pragma unroll
      for (int t = 0; t < 4; ++t) {
        int v = t * 512 + tid, row = v >> 4, c8 = (v & 15) * 8;
        *(bf16x8*)(Ct + (size_t)(n0 + row) * NDIM + m0 + c8) = *(bf16x8*)&tileT[row][c8];
      }
    }
    return;
  }

  // ------------------ consumer: 64x64 quadrant, 16 MFMA/chunk -------------
  int wr = wave & 1, wc = wave >> 1;
  uint32_t roff = (uint32_t)(q * 256 + ((rl ^ (q * 2)) * 16));   // swizzled frag
  uint32_t abase = lds_off(smem) + wr * 4096 + roff;
  uint32_t bbase = lds_off(smem) + 8192 + wc * 4096 + roff;

  f32x4 acc[4][4];
#pragma unroll
  for (int i = 0; i < 4; ++i)
#pragma unroll
    for (int j = 0; j < 4; ++j) acc[i][j] = (f32x4){0.f, 0.f, 0.f, 0.f};

#define CCOMPUTE(bb)                                                           \
  {                                                                            \
    asm volatile("s_barrier" ::: "memory");                                    \
    uint32_t av = abase + (bb) * 16384;                                        \
    uint32_t bv = bbase + (bb) * 16384;                                        \
    bf16x8 a0, a1, a2, a3, b0, b1, b2, b3;                                     \
    asm volatile("ds_read_b128 %0, %1"             : "=v"(a0) : "v"(av));      \
    asm volatile("ds_read_b128 %0, %1 offset:1024" : "=v"(a1) : "v"(av));      \
    asm volatile("ds_read_b128 %0, %1 offset:2048" : "=v"(a2) : "v"(av));      \
    asm volatile("ds_read_b128 %0, %1 offset:3072" : "=v"(a3) : "v"(av));      \
    asm volatile("ds_read_b128 %0, %1"             : "=v"(b0) : "v"(bv));      \
    asm volatile("ds_read_b128 %0, %1 offset:1024" : "=v"(b1) : "v"(bv));      \
    asm volatile("ds_read_b128 %0, %1 offset:2048" : "=v"(b2) : "v"(bv));      \
    asm volatile("ds_read_b128 %0, %1 offset:3072" : "=v"(b3) : "v"(bv));      \
    asm volatile("s_waitcnt lgkmcnt(0)"                                        \
                 : "+v"(a0), "+v"(a1), "+v"(a2), "+v"(a3), "+v"(b0),           \
                   "+v"(b1), "+v"(b2), "+v"(b3));                              \
    acc[0][0] = __builtin_amdgcn_mfma_f32_16x16x32_bf16(a0, b0, acc[0][0], 0, 0, 0); \
    acc[0][1] = __builtin_amdgcn_mfma_f32_16x16x32_bf16(a0, b1, acc[0][1], 0, 0, 0); \
    acc[0][2] = __builtin_amdgcn_mfma_f32_16x16x32_bf16(a0, b2, acc[0][2], 0, 0, 0); \
    acc[0][3] = __builtin_amdgcn_mfma_f32_16x16x32_bf16(a0, b3, acc[0][3], 0, 0, 0); \
    acc[1][0] = __builtin_amdgcn_mfma_f32_16x16x32_bf16(a1, b0, acc[1][0], 0, 0, 0); \
    acc[1][1] = __builtin_amdgcn_mfma_f32_16x16x32_bf16(a1, b1, acc[1][1], 0, 0, 0); \
    acc[1][2] = __builtin_amdgcn_mfma_f32_16x16x32_bf16(a1, b2, acc[1][2], 0, 0, 0); \
    acc[1][3] = __builtin_amdgcn_mfma_f32_16x16x32_bf16(a1, b3, acc[1][3], 0, 0, 0); \
    acc[2][0] = __builtin_amdgcn_mfma_f32_16x16x32_bf16(a2, b0, acc[2][0], 0, 0, 0); \
    acc[2][1] = __builtin_amdgcn_mfma_f32_16x16x32_bf16(a2, b1, acc[2][1], 0, 0, 0); \
    acc[2][2] = __builtin_amdgcn_mfma_f32_16x16x32_bf16(a2, b2, acc[2][2], 0, 0, 0); \
    acc[2][3] = __builtin_amdgcn_mfma_f32_16x16x32_bf16(a2, b3, acc[2][3], 0, 0, 0); \
    acc[3][0] = __builtin_amdgcn_mfma_f32_16x16x32_bf16(a3, b0, acc[3][0], 0, 0, 0); \
    acc[3][1] = __builtin_amdgcn_mfma_f32_16x16x32_bf16(a3, b1, acc[3][1], 0, 0, 0); \
    acc[3][2] = __builtin_amdgcn_mfma_f32_16x16x32_bf16(a3, b2, acc[3][2], 0, 0, 0); \
    acc[3][3] = __builtin_amdgcn_mfma_f32_16x16x32_bf16(a3, b3, acc[3][3], 0, 0, 0); \
  }

#pragma unroll 1
  for (int k = 0; k < 64; k += 4) {
    CCOMPUTE(0);
    CCOMPUTE(1);
    CCOMPUTE(2);
    CCOMPUTE(3);
  }
#undef CCOMPUTE

  // normal-orientation store (C[m][n]); C/D layout: col=lane&15, row=q*4+reg
#pragma unroll
  for (int i = 0; i < 4; ++i)
#pragma unroll
    for (int j = 0; j < 4; ++j)
#pragma unroll
      for (int r = 0; r < 4; ++r)
        C[(size_t)(m0 + wr * 64 + i * 16 + q * 4 + r) * NDIM + n0 + wc * 64 + j * 16 + rl] =
            (bf16_t)acc[i][j][r];

  // optional transposed store (Ct[n][m]) via LDS round-trip
  if (Ct) {
    __syncthreads();
    bf16_t (*tileT)[136] = (bf16_t(*)[136])smem;   // 128 x 136 x 2 B = 34.8 KB
#pragma unroll
    for (int i = 0; i < 4; ++i)
#pragma unroll
      for (int j = 0; j < 4; ++j)
#pragma unroll
        for (int r = 0; r < 4; ++r)
          tileT[wc * 64 + j * 16 + rl][wr * 64 + i * 16 + q * 4 + r] = (bf16_t)acc[i][j][r];
    __syncthreads();
#pragma unroll
    for (int t = 0; t < 4; ++t) {
      int v = t * 512 + tid, row = v >> 4, c8 = (v & 15) * 8;
      *(bf16x8*)(Ct + (size_t)(n0 + row) * NDIM + m0 + c8) = *(bf16x8*)&tileT[row][c8];
    }
  }
}

// ---------------------------------------------------------------------------
// skinny v5: C[64,16] = add + sign*(A[64,2048] @ Bt^T cols n0..+15).
// Panel (64 KB, fragment order) staged async; waves 0-3 K-half0 / 4-7 K-half1;
// 8 round-robin accumulators; LDS f32 reduction joins halves.
// megaA fusion params: Ablk = blocked A input (quad layout, agent-coherent);
// oblk_agent = blocked agent-store output + arrive counter; waitc = spin
// until 128 producer arrivals before consuming Ablk.
// ---------------------------------------------------------------------------
__device__ __forceinline__ void skinny_role(
    const bf16_t* __restrict__ A, const bf16_t* __restrict__ Ablk,
    const bf16_t* __restrict__ Bt, int n0, char* smem,
    const float* __restrict__ add, float sign,
    float* o32, float* o32b, bf16_t* o16, bf16_t* o16blk,
    bf16_t* oblk_agent, int* arrive, int* waitc) {
  int tid = threadIdx.x, lane = tid & 63, wave = tid >> 6;
  int rl = lane & 15, q = lane >> 4;
#pragma unroll
  for (int i = 0; i < 8; ++i) {
    const bf16_t* g = Bt + (size_t)(n0 + rl) * NDIM + (i * 8 + wave) * 32 + q * 8;
    gload16(g, smem + (size_t)(i * 512 + wave * 64) * 16);
  }
  __syncthreads();
  if (waitc) {              // wait for blocked-A producers (agent-coherent)
    if (tid == 0)
      while (__hip_atomic_load(waitc, __ATOMIC_RELAXED, __HIP_MEMORY_SCOPE_AGENT) < 128)
        __builtin_amdgcn_s_sleep(1);
    __syncthreads();
  }

  int ms = (wave & 3) * 16, kh = wave >> 2;
  const bf16x8* Ap = A ? (const bf16x8*)(A + (size_t)(ms + rl) * NDIM) + q + kh * 128 : nullptr;
  const bf16x8* Az = Ablk ? (const bf16x8*)Ablk +
      ((ms + rl) * 2 + (q & 1) + (q >> 1) * 128 + kh * 8192) : nullptr;
  const bf16x8* Bp = (const bf16x8*)smem + lane + kh * 2048;

  f32x4 acc[8];
#pragma unroll
  for (int i = 0; i < 8; ++i) acc[i] = (f32x4){0.f, 0.f, 0.f, 0.f};
  if (Ablk) {
#pragma unroll
    for (int c = 0; c < 32; ++c)
      acc[c & 7] = __builtin_amdgcn_mfma_f32_16x16x32_bf16(Az[c * 256], Bp[c * 64], acc[c & 7], 0, 0, 0);
  } else {
#pragma unroll
    for (int c = 0; c < 32; ++c)
      acc[c & 7] = __builtin_amdgcn_mfma_f32_16x16x32_bf16(Ap[c * 4], Bp[c * 64], acc[c & 7], 0, 0, 0);
  }
  f32x4 s = ((acc[0] + acc[1]) + (acc[2] + acc[3])) + ((acc[4] + acc[5]) + (acc[6] + acc[7]));

  f32x4* red = (f32x4*)(smem + 65536);
  bf16_t* pack = (bf16_t*)(smem + 69632);
  if (wave >= 4) red[(wave & 3) * 64 + lane] = s;
  __syncthreads();
  if (wave < 4) {
    s += red[wave * 64 + lane];
    int mrow = ms + q * 4, col = n0 + rl;
#pragma unroll
    for (int r = 0; r < 4; ++r) {
      size_t o = (size_t)(mrow + r) * NDIM + col;
      float v = sign * s[r];
      if (add) v += add[o];
      if (o32)  o32[o]  = v;
      if (o32b) o32b[o] = v;
      if (o16)  o16[o]  = (bf16_t)v;
      if (o16blk) o16blk[(size_t)(n0 >> 4) * 1024 + (mrow + r) * 16 + rl] = (bf16_t)v;
      if (oblk_agent) pack[(mrow + r) * 16 + rl] = (bf16_t)v;
    }
  }
  if (oblk_agent) {
    __syncthreads();                     // panel pack complete in LDS
    if (tid < 128) {                     // coalesced 16B/lane agent stores
      int row = tid >> 1, hf = tid & 1;
      const u64_t* src = (const u64_t*)pack + row * 4 + hf * 2;
      u64_t* dst = (u64_t*)(oblk_agent + (size_t)(n0 >> 4) * 1024) + row * 4 + hf * 2;
      __hip_atomic_store(dst,     src[0], __ATOMIC_RELAXED, __HIP_MEMORY_SCOPE_AGENT);
      __hip_atomic_store(dst + 1, src[1], __ATOMIC_RELAXED, __HIP_MEMORY_SCOPE_AGENT);
    }
    __syncthreads();                     // vmcnt(0): stores at coherence point
    if (arrive && tid == 0)
      __hip_atomic_fetch_add(arrive, 1, __ATOMIC_RELAXED, __HIP_MEMORY_SCOPE_AGENT);
  }
}

// --------------------------- mega nodes (512 thr) --------------------------
// A (fused, 640 blocks): W = U@invM dual store (256 wgemm) || yMF = y@H^T
// (128, blocked agent out + arrive) || c = yMF@invM (128, waits) || x0 =
// yMF@Dinv (128, waits -> z0).  Deadlock-free: 256 waiting consumers < 512
// resident capacity, and wgemm/producer blocks always retire.
__global__ __launch_bounds__(512, 4) void megaA(
    const bf16_t* __restrict__ U16, const bf16_t* __restrict__ iMt16,
    const bf16_t* __restrict__ Dt16,
    const bf16_t* __restrict__ y16, const bf16_t* __restrict__ H16,
    bf16_t* __restrict__ Wrm, bf16_t* __restrict__ Wt, bf16_t* __restrict__ yMFblk,
    float* __restrict__ c32, bf16_t* __restrict__ c16, bf16_t* __restrict__ z0,
    int* __restrict__ barA) {
  __shared__ char smem[SMEM_BYTES];
  int b = blockIdx.x;
  if (b < 256)      wgemm_role(U16, iMt16, Wrm, Wt, b, smem);
  else if (b < 384) skinny_role(y16, nullptr, H16, (b - 256) * 16, smem, nullptr, 1.f,
                                nullptr, nullptr, nullptr, nullptr, yMFblk, barA, nullptr);
  else if (b < 512) skinny_role(nullptr, yMFblk, iMt16, (b - 384) * 16, smem, nullptr, 1.f,
                                c32, nullptr, c16, nullptr, nullptr, nullptr, barA);
  else              skinny_role(nullptr, yMFblk, Dt16, (b - 512) * 16, smem, nullptr, 1.f,
                                nullptr, nullptr, z0, nullptr, nullptr, nullptr, barA);
}

// C: W2 = NT(Wt,Wrm), dual store W2t+W2rm (256) || x1 (128 -> traj[1], z0+BSN)
//    || c2 (128)
__global__ __launch_bounds__(512, 4) void megaC(
    const bf16_t* __restrict__ Wt, const bf16_t* __restrict__ Wrm,
    const bf16_t* __restrict__ z0, const bf16_t* __restrict__ c16,
    const float* __restrict__ c32,
    bf16_t* __restrict__ W2t, bf16_t* __restrict__ W2rm,
    float* __restrict__ traj1, bf16_t* __restrict__ z0b,
    float* __restrict__ c2_32, bf16_t* __restrict__ c2_16) {
  __shared__ char smem[SMEM_BYTES];
  int b = blockIdx.x;
  if (b < 256)      wgemm_role(Wt, Wrm, W2t, W2rm, b, smem);
  else if (b < 384) skinny_role(z0, nullptr, Wt, (b - 256) * 16, smem, c32, -1.f,
                                traj1, nullptr, z0b, nullptr, nullptr, nullptr, nullptr);
  else              skinny_role(c16, nullptr, Wt, (b - 384) * 16, smem, c32, -1.f,
                                c2_32, nullptr, c2_16, nullptr, nullptr, nullptr, nullptr);
}

// D (light): x2 (128 -> traj[2], zA row + blk) || x3 (128 -> traj[3]) || c4 (128)
__global__ __launch_bounds__(512, 4) void megaD(
    const bf16_t* __restrict__ W2t, const bf16_t* __restrict__ z0,
    const bf16_t* __restrict__ c2_16, const float* __restrict__ c2_32,
    float* __restrict__ traj2, float* __restrict__ traj3,
    bf16_t* __restrict__ zA, bf16_t* __restrict__ zAblk, float* __restrict__ c4_32) {
  __shared__ char smem[SMEM_BYTES];
  int b = blockIdx.x;
  if (b < 128)      skinny_role(z0, nullptr, W2t, b * 16, smem, c2_32, 1.f,
                                traj2, nullptr, zA, zAblk, nullptr, nullptr, nullptr);
  else if (b < 256) skinny_role(z0 + BSN, nullptr, W2t, (b - 128) * 16, smem, c2_32, 1.f,
                                traj3, nullptr, zA + BSN, zAblk + BSN, nullptr, nullptr, nullptr);
  else              skinny_role(c2_16, nullptr, W2t, (b - 256) * 16, smem, c2_32, 1.f,
                                c4_32, nullptr, nullptr, nullptr, nullptr, nullptr, nullptr);
}

// E: W4t = NT(W2t,W2rm) (256) || x4 (128 -> traj[4], blk chain2) || x5 (128 -> traj[5], blk chain3)
__global__ __launch_bounds__(512, 4) void megaE(
    const bf16_t* __restrict__ W2t, const bf16_t* __restrict__ W2rm,
    const bf16_t* __restrict__ zA_in, const float* __restrict__ c2_32,
    bf16_t* __restrict__ W4t, float* __restrict__ traj4, float* __restrict__ traj5,
    bf16_t* __restrict__ zAblk) {
  __shared__ char smem[SMEM_BYTES];
  int b = blockIdx.x;
  if (b < 256)      wgemm_role(W2t, W2rm, W4t, nullptr, b, smem);
  else if (b < 384) skinny_role(zA_in, nullptr, W2t, (b - 256) * 16, smem, c2_32, 1.f,
                                traj4, nullptr, nullptr, zAblk + 2 * BSN, nullptr, nullptr, nullptr);
  else              skinny_role(zA_in + BSN, nullptr, W2t, (b - 384) * 16, smem, c2_32, 1.f,
                                traj5, nullptr, nullptr, zAblk + 3 * BSN, nullptr, nullptr, nullptr);
}

// ---------------------------------------------------------------------------
// quad_fused v4 (unchanged -- matched prediction): all 5 quad steps in one
// fence-free launch; blocked write-through hand-off; per-(step,chain)
// relaxed counters.
// ---------------------------------------------------------------------------
__global__ __launch_bounds__(512, 4) void quad_fused(
    const bf16_t* __restrict__ zblk_in, const bf16_t* __restrict__ W4t,
    const float* __restrict__ c4_32, float* __restrict__ traj6,
    bf16_t* __restrict__ zsteps, float* __restrict__ sfin, int* __restrict__ bar) {
  __shared__ char smem[SMEM_BYTES];
  int b = blockIdx.x, ci = b & 3, p = b >> 2;
  int tid = threadIdx.x, lane = tid & 63, wave = tid >> 6;
  int rl = lane & 15, q = lane >> 4;
  int n0 = p * 16;
  // stage W4t panel once (fragment order), reused for all 5 steps
#pragma unroll
  for (int i = 0; i < 8; ++i) {
    const bf16_t* g = W4t + (size_t)(n0 + rl) * NDIM + (i * 8 + wave) * 32 + q * 8;
    gload16(g, smem + (size_t)(i * 512 + wave * 64) * 16);
  }
  __syncthreads();

  int ms = (wave & 3) * 16, kh = wave >> 2;
  const bf16x8* Bp = (const bf16x8*)smem + lane + kh * 2048;
  f32x4*  red  = (f32x4*)(smem + 65536);   // 4 KB
  bf16_t* pack = (bf16_t*)(smem + 69632);  // 2 KB panel pack
  const bf16_t* zcur = zblk_in + (size_t)ci * BSN;
  // per-thread blocked A offset in bf16x8 units
  int aoff = (ms + rl) * 2 + (q & 1) + (q >> 1) * 128 + kh * 8192;

#pragma unroll 1
  for (int g = 0; g < 5; ++g) {
    const bf16x8* Az = (const bf16x8*)zcur + aoff;
    f32x4 acc[8];
#pragma unroll
    for (int i = 0; i < 8; ++i) acc[i] = (f32x4){0.f, 0.f, 0.f, 0.f};
#pragma unroll
    for (int c = 0; c < 32; ++c)
      acc[c & 7] = __builtin_amdgcn_mfma_f32_16x16x32_bf16(Az[c * 256], Bp[c * 64], acc[c & 7], 0, 0, 0);
    f32x4 s = ((acc[0] + acc[1]) + (acc[2] + acc[3])) + ((acc[4] + acc[5]) + (acc[6] + acc[7]));

    if (wave >= 4) red[(wave & 3) * 64 + lane] = s;
    __syncthreads();
    bf16_t* zn = zsteps + (size_t)g * ZSTRIDE + (size_t)ci * BSN;  // fresh blocked buffer
    if (wave < 4) {
      s += red[wave * 64 + lane];
      int mrow = ms + q * 4, col = n0 + rl;
      float* tj = traj6 + (size_t)(4 * g + ci) * BSN;
#pragma unroll
      for (int r = 0; r < 4; ++r) {
        size_t o = (size_t)(mrow + r) * NDIM + col;
        float v = c4_32[o] + s[r];
        tj[o] = v;
        if (g == 4 && ci == 3) sfin[o] = v;
        if (g < 4) pack[(mrow + r) * 16 + rl] = (bf16_t)v;
      }
    }
    if (g < 4) {
      __syncthreads();                     // panel pack complete in LDS
      if (tid < 128) {                     // coalesced 16B/lane agent stores
        int row = tid >> 1, hf = tid & 1;
        const u64_t* src = (const u64_t*)pack + row * 4 + hf * 2;
        u64_t* dst = (u64_t*)(zn + (size_t)p * 1024) + row * 4 + hf * 2;
        __hip_atomic_store(dst,     src[0], __ATOMIC_RELAXED, __HIP_MEMORY_SCOPE_AGENT);
        __hip_atomic_store(dst + 1, src[1], __ATOMIC_RELAXED, __HIP_MEMORY_SCOPE_AGENT);
      }
      __syncthreads();   // s_waitcnt vmcnt(0): all sc1 stores at coherence point
      if (tid == 0) {
        int* ctr = &bar[(g * 4 + ci) * 32];  // 128B-separated per (step,chain)
        __hip_atomic_fetch_add(ctr, 1, __ATOMIC_RELAXED, __HIP_MEMORY_SCOPE_AGENT);
        while (__hip_atomic_load(ctr, __ATOMIC_RELAXED, __HIP_MEMORY_SCOPE_AGENT) < 128)
          __builtin_amdgcn_s_sleep(1);
        asm volatile("" ::: "memory");     // no acquire fence: fresh buffer, no stale lines
      }
      __syncthreads();
      zcur = zn;
    }
  }
}

// ---------------------------------------------------------------------------
// Host driver: memset + 6 kernel nodes (megaB fused into megaA).
// ---------------------------------------------------------------------------
extern "C" void kernel_launch(void* const* d_in, const int* in_sizes, int n_in,
                              void* d_out, int out_size, void* d_ws, size_t ws_size,
                              hipStream_t stream) {
  const float* y    = (const float*)d_in[2];
  const float* H    = (const float*)d_in[3];
  const float* Dinv = (const float*)d_in[4];
  const float* U    = (const float*)d_in[5];
  const float* invM = (const float*)d_in[6];

  float* out     = (float*)d_out;
  float* s_final = out;
  float* traj    = out + BSN;

  char* ws = (char*)d_ws;
  size_t off = 0;
  auto alloc = [&](size_t bytes) -> void* {
    void* p = ws + off;
    off += (bytes + 255) & ~(size_t)255;
    return p;
  };
  bf16_t* U16   = (bf16_t*)alloc((size_t)NDIM * NDIM * 2);  // -> W2rm after megaA
  bf16_t* Dt16  = (bf16_t*)alloc((size_t)NDIM * NDIM * 2);  // -> W4t after megaA
  bf16_t* iMt16 = (bf16_t*)alloc((size_t)NDIM * NDIM * 2);
  bf16_t* H16   = (bf16_t*)alloc((size_t)NDIM * NDIM * 2);  // -> W2t after megaA
  bf16_t* Wrm   = (bf16_t*)alloc((size_t)NDIM * NDIM * 2);
  bf16_t* Wt    = (bf16_t*)alloc((size_t)NDIM * NDIM * 2);
  bf16_t* y16   = (bf16_t*)alloc(BSN * 2);
  bf16_t* yMFblk= (bf16_t*)alloc(BSN * 2);              // blocked, agent-coherent
  bf16_t* c16   = (bf16_t*)alloc(BSN * 2);
  bf16_t* c2_16 = (bf16_t*)alloc(BSN * 2);
  float*  c32   = (float*)alloc(BSN * 4);
  float*  c2_32 = (float*)alloc(BSN * 4);
  float*  c4_32 = (float*)alloc(BSN * 4);
  bf16_t* z0    = (bf16_t*)alloc(2 * BSN * 2);          // x0, x1 (row-major)
  bf16_t* zA    = (bf16_t*)alloc(2 * BSN * 2);          // x2, x3 row-major (megaE A-operand)
  bf16_t* zAblk = (bf16_t*)alloc(4 * BSN * 2);          // x2..x5 blocked (quad input)
  bf16_t* zsteps= (bf16_t*)alloc(5 * ZSTRIDE * 2);      // 5 fresh per-step blocked slabs
  int*    bar   = (int*)alloc(4096);                    // quad counters + megaA counter
  bf16_t* W2t   = H16;   // H16 dead after megaA
  bf16_t* W2rm  = U16;   // U16 dead after megaA
  bf16_t* W4t   = Dt16;  // Dt16 dead after megaA (consumed by its skinnies)
  int*    barA  = bar + 512;                            // separate cacheline region

  hipMemsetAsync(bar, 0, 4096, stream);

  prep<<<3072, 512, 0, stream>>>(H, U, Dinv, invM, y, H16, U16, Dt16, iMt16, y16, traj);
  megaA<<<640, 512, 0, stream>>>(U16, iMt16, Dt16, y16, H16, Wrm, Wt, yMFblk,
                                 c32, c16, z0, barA);
  megaC<<<512, 512, 0, stream>>>(Wt, Wrm, z0, c16, c32, W2t, W2rm,
                                 traj + BSN, z0 + BSN, c2_32, c2_16);
  megaD<<<384, 512, 0, stream>>>(W2t, z0, c2_16, c2_32, traj + 2 * BSN, traj + 3 * BSN,
                                 zA, zAblk, c4_32);
  megaE<<<512, 512, 0, stream>>>(W2t, W2rm, zA, c2_32, W4t, traj + 4 * BSN, traj + 5 * BSN,
                                 zAblk);

  // all 5 quad steps in one fence-free launch: fresh blocked slab per step,
  // writes traj[6..25] + s_final
  quad_fused<<<512, 512, 0, stream>>>(zAblk, W4t, c4_32, traj + 6 * BSN,
                                      zsteps, s_final, bar);
}

// Round 13
// 282.499 us; speedup vs baseline: 1.0307x; 1.0307x over previous
//
#include <hip/hip_runtime.h>
#include <hip/hip_bf16.h>

#define NDIM 2048
#define BS   64
#define NM4  (NDIM * NDIM / 4)
#define BSN  ((size_t)BS * NDIM)
#define ZSTRIDE ((size_t)4 * BSN + 2048)   // 4-chain z slab + 4KB pad
#define SMEM_BYTES 71680   // wgemm: 4x16KB A+B pipeline (+34.8KB tileT reuse); skinny: 64+4+2KB

typedef __bf16 bf16_t;
typedef __bf16 bf16x4 __attribute__((ext_vector_type(4)));
typedef __bf16 bf16x8 __attribute__((ext_vector_type(8)));
typedef float  f32x4  __attribute__((ext_vector_type(4)));
typedef unsigned long long u64_t;

// Async global->LDS, 16 B per lane.  LDS dest = wave-uniform base + lane*16.
__device__ __forceinline__ void gload16(const void* g, void* lds) {
  __builtin_amdgcn_global_load_lds(
      (const __attribute__((address_space(1))) void*)g,
      (__attribute__((address_space(3))) void*)lds, 16, 0, 0);
}
// 32-bit LDS byte offset of a generic pointer into __shared__.
__device__ __forceinline__ uint32_t lds_off(void* p) {
  return (uint32_t)(uintptr_t)(__attribute__((address_space(3))) void*)p;
}

// ---------------------------------------------------------------------------
// prep (512 thr, 3072 blocks): b<1024 convert H,U (+y, traj0); else 64x64
// fp32->bf16 vectorized transposes of Dinv, invM.
// ---------------------------------------------------------------------------
__global__ __launch_bounds__(512) void prep(
    const float* __restrict__ H, const float* __restrict__ U,
    const float* __restrict__ Dinv, const float* __restrict__ invM,
    const float* __restrict__ y,
    bf16_t* __restrict__ H16, bf16_t* __restrict__ U16,
    bf16_t* __restrict__ Dt, bf16_t* __restrict__ iMt,
    bf16_t* __restrict__ y16, float* __restrict__ traj0) {
  __shared__ bf16_t tile[64][72];
  int b = blockIdx.x, tid = threadIdx.x;
  if (b < 1024) {
#pragma unroll
    for (int i = 0; i < 4; ++i) {
      int idx = b * 2048 + i * 512 + tid;
      const float* src = (idx < NM4) ? H : U;
      bf16_t* dst = (idx < NM4) ? H16 : U16;
      int j = (idx < NM4) ? idx : idx - NM4;
      float4 v = ((const float4*)src)[j];
      bf16x4 o = {(bf16_t)v.x, (bf16_t)v.y, (bf16_t)v.z, (bf16_t)v.w};
      ((bf16x4*)dst)[j] = o;
    }
    int yi = b * 512 + tid;
    if (yi < BS * NDIM / 4) {
      float4 w = ((const float4*)y)[yi];
      bf16x4 o2 = {(bf16_t)w.x, (bf16_t)w.y, (bf16_t)w.z, (bf16_t)w.w};
      ((bf16x4*)y16)[yi] = o2;
      ((float4*)traj0)[yi] = make_float4(0.f, 0.f, 0.f, 0.f);
    }
  } else {
    int id = b - 1024;
    const float* src = (id < 1024) ? Dinv : invM;
    bf16_t* dst = (id < 1024) ? Dt : iMt;
    id &= 1023;
    int bx = id & 31, by = id >> 5;
    int r = tid >> 3, c8 = (tid & 7) * 8;
    const float* sp = src + (size_t)(by * 64 + r) * NDIM + bx * 64 + c8;
    float4 v0 = *(const float4*)sp;
    float4 v1 = *(const float4*)(sp + 4);
    bf16_t* t = &tile[r][c8];
    t[0] = (bf16_t)v0.x; t[1] = (bf16_t)v0.y; t[2] = (bf16_t)v0.z; t[3] = (bf16_t)v0.w;
    t[4] = (bf16_t)v1.x; t[5] = (bf16_t)v1.y; t[6] = (bf16_t)v1.z; t[7] = (bf16_t)v1.w;
    __syncthreads();
    bf16x8 o;
#pragma unroll
    for (int j = 0; j < 8; ++j) o[j] = tile[c8 + j][r];
    *(bf16x8*)(dst + (size_t)(bx * 64 + r) * NDIM + by * 64 + c8) = o;
  }
}

// ---------------------------------------------------------------------------
// wgemm v11 (v9 + pair-wise sync cadence): 2048^3 NT GEMM, 512 thr, 128x128
// tile, BK=32, 64 chunks, 4x16KB buffers.
// r9 post-mortem: conflicted(v6) == conflict-free(v9) == 33us kills the LDS
// hypotheses; L2/HBM models are ~8-10us.  Surviving hypothesis: per-chunk
// barrier cadence (64 sync cycles x fixed skew/latency cost).  v11 halves the
// sync count with the SAME buffers/macros: pair i = chunks {2i,2i+1} ->
// buffers {2(i&1), 2(i&1)+1} (pair-wise double buffer).
//   producer: {write 2 chunks, load 2 chunks ahead, lgkmcnt(0)+barrier} x32
//   consumer: {barrier, CCOMPUTE x2} x32
// WAR-safe: pair i+1 uses the opposite buffer pair; pair i+2 written only
// after barrier #(i+1) when consumer finished pair i.  Barriers 32==32.
// ---------------------------------------------------------------------------
__device__ __forceinline__ void wgemm_role(
    const bf16_t* __restrict__ A, const bf16_t* __restrict__ Bt,
    bf16_t* __restrict__ C, bf16_t* __restrict__ Ct, int blk, char* smem) {
  int tid = threadIdx.x, lane = tid & 63, wave = tid >> 6;
  int xcd = blk & 7, jj = blk >> 3;
  int m0 = (((xcd >> 1) << 2) + (jj >> 3)) * 128;
  int n0 = (((xcd & 1) << 3) + (jj & 7)) * 128;
  int rl = lane & 15, q = lane >> 4;

  if (wave >= 4) {
    // ---- producer: coalesced reg loads, swizzled conflict-free ds_write ---
    int pw = wave - 4;
    int prow = lane >> 2, pkg = lane & 3;      // 4-lane 64B runs
    const bf16_t* PA0 = A  + (size_t)(m0 + pw * 32 + prow) * NDIM + pkg * 8;
    const bf16_t* PA1 = PA0 + 16 * NDIM;
    const bf16_t* PB0 = Bt + (size_t)(n0 + pw * 32 + prow) * NDIM + pkg * 8;
    const bf16_t* PB1 = PB0 + 16 * NDIM;
    char* WA = smem + pw * 2048 + (pkg * 256 + ((prow ^ (pkg * 2)) * 16));

    bf16x8 rE[4], rO[4];
#define PLOAD(R, s)                                  \
    {                                                \
      int _k = (s) * 32;                             \
      R[0] = *(const bf16x8*)(PA0 + _k);             \
      R[1] = *(const bf16x8*)(PA1 + _k);             \
      R[2] = *(const bf16x8*)(PB0 + _k);             \
      R[3] = *(const bf16x8*)(PB1 + _k);             \
    }
#define PWRITE(R, BUF)                               \
    {                                                \
      char* _w = WA + (BUF) * 16384;                 \
      *(bf16x8*)(_w)        = R[0];                  \
      *(bf16x8*)(_w + 1024) = R[1];                  \
      *(bf16x8*)(_w + 8192) = R[2];                  \
      *(bf16x8*)(_w + 9216) = R[3];                  \
    }
#define LB asm volatile("s_waitcnt lgkmcnt(0)\n\ts_barrier" ::: "memory")
    PLOAD(rE, 0); PLOAD(rO, 1);
    PWRITE(rE, 0); PLOAD(rE, 2);
    PWRITE(rO, 1); PLOAD(rO, 3);
    LB;                                    // #0: pair0 (bufs 0,1) ready
#pragma unroll 1
    for (int i = 1; i < 31; ++i) {
      int bb = (i & 1) * 2;
      PWRITE(rE, bb);     PLOAD(rE, 2 * i + 2);
      PWRITE(rO, bb + 1); PLOAD(rO, 2 * i + 3);
      LB;                                  // #i: pair i ready
    }
    PWRITE(rE, 2); PWRITE(rO, 3);          // pair 31 (chunks 62,63)
    LB;                                    // #31
#undef LB
#undef PWRITE
#undef PLOAD
    if (Ct) {
      __syncthreads();   // consumers writing tileT
      __syncthreads();
      bf16_t (*tileT)[136] = (bf16_t(*)[136])smem;
#pragma unroll
      for (int t = 0; t < 4; ++t) {
        int v = t * 512 + tid, row = v >> 4, c8 = (v & 15) * 8;
        *(bf16x8*)(Ct + (size_t)(n0 + row) * NDIM + m0 + c8) = *(bf16x8*)&tileT[row][c8];
      }
    }
    return;
  }

  // ------------------ consumer: 64x64 quadrant, 16 MFMA/chunk -------------
  int wr = wave & 1, wc = wave >> 1;
  uint32_t roff = (uint32_t)(q * 256 + ((rl ^ (q * 2)) * 16));   // swizzled frag
  uint32_t abase = lds_off(smem) + wr * 4096 + roff;
  uint32_t bbase = lds_off(smem) + 8192 + wc * 4096 + roff;

  f32x4 acc[4][4];
#pragma unroll
  for (int i = 0; i < 4; ++i)
#pragma unroll
    for (int j = 0; j < 4; ++j) acc[i][j] = (f32x4){0.f, 0.f, 0.f, 0.f};

#define CCOMPUTE(bb)                                                           \
  {                                                                            \
    uint32_t av = abase + (bb) * 16384;                                        \
    uint32_t bv = bbase + (bb) * 16384;                                        \
    bf16x8 a0, a1, a2, a3, b0, b1, b2, b3;                                     \
    asm volatile("ds_read_b128 %0, %1"             : "=v"(a0) : "v"(av));      \
    asm volatile("ds_read_b128 %0, %1 offset:1024" : "=v"(a1) : "v"(av));      \
    asm volatile("ds_read_b128 %0, %1 offset:2048" : "=v"(a2) : "v"(av));      \
    asm volatile("ds_read_b128 %0, %1 offset:3072" : "=v"(a3) : "v"(av));      \
    asm volatile("ds_read_b128 %0, %1"             : "=v"(b0) : "v"(bv));      \
    asm volatile("ds_read_b128 %0, %1 offset:1024" : "=v"(b1) : "v"(bv));      \
    asm volatile("ds_read_b128 %0, %1 offset:2048" : "=v"(b2) : "v"(bv));      \
    asm volatile("ds_read_b128 %0, %1 offset:3072" : "=v"(b3) : "v"(bv));      \
    asm volatile("s_waitcnt lgkmcnt(0)"                                        \
                 : "+v"(a0), "+v"(a1), "+v"(a2), "+v"(a3), "+v"(b0),           \
                   "+v"(b1), "+v"(b2), "+v"(b3));                              \
    acc[0][0] = __builtin_amdgcn_mfma_f32_16x16x32_bf16(a0, b0, acc[0][0], 0, 0, 0); \
    acc[0][1] = __builtin_amdgcn_mfma_f32_16x16x32_bf16(a0, b1, acc[0][1], 0, 0, 0); \
    acc[0][2] = __builtin_amdgcn_mfma_f32_16x16x32_bf16(a0, b2, acc[0][2], 0, 0, 0); \
    acc[0][3] = __builtin_amdgcn_mfma_f32_16x16x32_bf16(a0, b3, acc[0][3], 0, 0, 0); \
    acc[1][0] = __builtin_amdgcn_mfma_f32_16x16x32_bf16(a1, b0, acc[1][0], 0, 0, 0); \
    acc[1][1] = __builtin_amdgcn_mfma_f32_16x16x32_bf16(a1, b1, acc[1][1], 0, 0, 0); \
    acc[1][2] = __builtin_amdgcn_mfma_f32_16x16x32_bf16(a1, b2, acc[1][2], 0, 0, 0); \
    acc[1][3] = __builtin_amdgcn_mfma_f32_16x16x32_bf16(a1, b3, acc[1][3], 0, 0, 0); \
    acc[2][0] = __builtin_amdgcn_mfma_f32_16x16x32_bf16(a2, b0, acc[2][0], 0, 0, 0); \
    acc[2][1] = __builtin_amdgcn_mfma_f32_16x16x32_bf16(a2, b1, acc[2][1], 0, 0, 0); \
    acc[2][2] = __builtin_amdgcn_mfma_f32_16x16x32_bf16(a2, b2, acc[2][2], 0, 0, 0); \
    acc[2][3] = __builtin_amdgcn_mfma_f32_16x16x32_bf16(a2, b3, acc[2][3], 0, 0, 0); \
    acc[3][0] = __builtin_amdgcn_mfma_f32_16x16x32_bf16(a3, b0, acc[3][0], 0, 0, 0); \
    acc[3][1] = __builtin_amdgcn_mfma_f32_16x16x32_bf16(a3, b1, acc[3][1], 0, 0, 0); \
    acc[3][2] = __builtin_amdgcn_mfma_f32_16x16x32_bf16(a3, b2, acc[3][2], 0, 0, 0); \
    acc[3][3] = __builtin_amdgcn_mfma_f32_16x16x32_bf16(a3, b3, acc[3][3], 0, 0, 0); \
  }

#pragma unroll 1
  for (int k = 0; k < 32; ++k) {
    int bb = (k & 1) * 2;
    asm volatile("s_barrier" ::: "memory");
    CCOMPUTE(bb);
    CCOMPUTE(bb + 1);
  }
#undef CCOMPUTE

  // normal-orientation store (C[m][n]); C/D layout: col=lane&15, row=q*4+reg
#pragma unroll
  for (int i = 0; i < 4; ++i)
#pragma unroll
    for (int j = 0; j < 4; ++j)
#pragma unroll
      for (int r = 0; r < 4; ++r)
        C[(size_t)(m0 + wr * 64 + i * 16 + q * 4 + r) * NDIM + n0 + wc * 64 + j * 16 + rl] =
            (bf16_t)acc[i][j][r];

  // optional transposed store (Ct[n][m]) via LDS round-trip
  if (Ct) {
    __syncthreads();
    bf16_t (*tileT)[136] = (bf16_t(*)[136])smem;   // 128 x 136 x 2 B = 34.8 KB
#pragma unroll
    for (int i = 0; i < 4; ++i)
#pragma unroll
      for (int j = 0; j < 4; ++j)
#pragma unroll
        for (int r = 0; r < 4; ++r)
          tileT[wc * 64 + j * 16 + rl][wr * 64 + i * 16 + q * 4 + r] = (bf16_t)acc[i][j][r];
    __syncthreads();
#pragma unroll
    for (int t = 0; t < 4; ++t) {
      int v = t * 512 + tid, row = v >> 4, c8 = (v & 15) * 8;
      *(bf16x8*)(Ct + (size_t)(n0 + row) * NDIM + m0 + c8) = *(bf16x8*)&tileT[row][c8];
    }
  }
}

// ---------------------------------------------------------------------------
// skinny v4 (r9 form): C[64,16] = add + sign*(A[64,2048] @ Bt^T cols n0..+15).
// Panel (64 KB, fragment order) staged async; waves 0-3 K-half0 / 4-7 K-half1;
// 8 round-robin accumulators; LDS f32 reduction joins halves.
// o16blk: optional BLOCKED bf16 store (panel-contiguous [p][64][16]).
// ---------------------------------------------------------------------------
__device__ __forceinline__ void skinny_role(
    const bf16_t* __restrict__ A, const bf16_t* __restrict__ Bt, int n0, char* smem,
    const float* __restrict__ add, float sign,
    float* o32, float* o32b, bf16_t* o16, bf16_t* o16blk) {
  int tid = threadIdx.x, lane = tid & 63, wave = tid >> 6;
  int rl = lane & 15, q = lane >> 4;
#pragma unroll
  for (int i = 0; i < 8; ++i) {
    const bf16_t* g = Bt + (size_t)(n0 + rl) * NDIM + (i * 8 + wave) * 32 + q * 8;
    gload16(g, smem + (size_t)(i * 512 + wave * 64) * 16);
  }
  __syncthreads();

  int ms = (wave & 3) * 16, kh = wave >> 2;
  const bf16x8* Ap = (const bf16x8*)(A + (size_t)(ms + rl) * NDIM) + q + kh * 128;
  const bf16x8* Bp = (const bf16x8*)smem + lane + kh * 2048;

  f32x4 acc[8];
#pragma unroll
  for (int i = 0; i < 8; ++i) acc[i] = (f32x4){0.f, 0.f, 0.f, 0.f};
#pragma unroll
  for (int c = 0; c < 32; ++c)
    acc[c & 7] = __builtin_amdgcn_mfma_f32_16x16x32_bf16(Ap[c * 4], Bp[c * 64], acc[c & 7], 0, 0, 0);
  f32x4 s = ((acc[0] + acc[1]) + (acc[2] + acc[3])) + ((acc[4] + acc[5]) + (acc[6] + acc[7]));

  f32x4* red = (f32x4*)(smem + 65536);
  if (wave >= 4) red[(wave & 3) * 64 + lane] = s;
  __syncthreads();
  if (wave < 4) {
    s += red[wave * 64 + lane];
    int mrow = ms + q * 4, col = n0 + rl;
#pragma unroll
    for (int r = 0; r < 4; ++r) {
      size_t o = (size_t)(mrow + r) * NDIM + col;
      float v = sign * s[r];
      if (add) v += add[o];
      if (o32)  o32[o]  = v;
      if (o32b) o32b[o] = v;
      if (o16)  o16[o]  = (bf16_t)v;
      if (o16blk) o16blk[(size_t)(n0 >> 4) * 1024 + (mrow + r) * 16 + rl] = (bf16_t)v;
    }
  }
}

// --------------------------- mega nodes (512 thr) --------------------------
// A: W = U@invM, dual store Wrm+Wt (256 wgemm) || yMF = y@H^T (128 skinny)
__global__ __launch_bounds__(512, 4) void megaA(
    const bf16_t* __restrict__ U16, const bf16_t* __restrict__ iMt16,
    const bf16_t* __restrict__ y16, const bf16_t* __restrict__ H16,
    bf16_t* __restrict__ Wrm, bf16_t* __restrict__ Wt, bf16_t* __restrict__ yMF16) {
  __shared__ char smem[SMEM_BYTES];
  int b = blockIdx.x;
  if (b < 256) wgemm_role(U16, iMt16, Wrm, Wt, b, smem);
  else         skinny_role(y16, H16, (b - 256) * 16, smem, nullptr, 1.f,
                           nullptr, nullptr, yMF16, nullptr);
}

// B (light): c = yMF@invM (128) || x0 = yMF@Dinv (128 -> z0)
__global__ __launch_bounds__(512, 4) void megaB(
    const bf16_t* __restrict__ yMF16, const bf16_t* __restrict__ iMt16,
    const bf16_t* __restrict__ Dt16,
    float* __restrict__ c32, bf16_t* __restrict__ c16, bf16_t* __restrict__ z0) {
  __shared__ char smem[SMEM_BYTES];
  int b = blockIdx.x;
  if (b < 128) skinny_role(yMF16, iMt16, b * 16, smem, nullptr, 1.f, c32, nullptr, c16, nullptr);
  else         skinny_role(yMF16, Dt16, (b - 128) * 16, smem, nullptr, 1.f, nullptr, nullptr, z0, nullptr);
}

// C: W2 = NT(Wt,Wrm), dual store W2t+W2rm (256) || x1 (128 -> traj[1], z0+BSN)
//    || c2 (128)
__global__ __launch_bounds__(512, 4) void megaC(
    const bf16_t* __restrict__ Wt, const bf16_t* __restrict__ Wrm,
    const bf16_t* __restrict__ z0, const bf16_t* __restrict__ c16,
    const float* __restrict__ c32,
    bf16_t* __restrict__ W2t, bf16_t* __restrict__ W2rm,
    float* __restrict__ traj1, bf16_t* __restrict__ z0b,
    float* __restrict__ c2_32, bf16_t* __restrict__ c2_16) {
  __shared__ char smem[SMEM_BYTES];
  int b = blockIdx.x;
  if (b < 256)      wgemm_role(Wt, Wrm, W2t, W2rm, b, smem);
  else if (b < 384) skinny_role(z0, Wt, (b - 256) * 16, smem, c32, -1.f, traj1, nullptr, z0b, nullptr);
  else              skinny_role(c16, Wt, (b - 384) * 16, smem, c32, -1.f, c2_32, nullptr, c2_16, nullptr);
}

// D (light): x2 (128 -> traj[2], zA row + blk) || x3 (128 -> traj[3]) || c4 (128)
__global__ __launch_bounds__(512, 4) void megaD(
    const bf16_t* __restrict__ W2t, const bf16_t* __restrict__ z0,
    const bf16_t* __restrict__ c2_16, const float* __restrict__ c2_32,
    float* __restrict__ traj2, float* __restrict__ traj3,
    bf16_t* __restrict__ zA, bf16_t* __restrict__ zAblk, float* __restrict__ c4_32) {
  __shared__ char smem[SMEM_BYTES];
  int b = blockIdx.x;
  if (b < 128)      skinny_role(z0, W2t, b * 16, smem, c2_32, 1.f, traj2, nullptr, zA, zAblk);
  else if (b < 256) skinny_role(z0 + BSN, W2t, (b - 128) * 16, smem, c2_32, 1.f, traj3, nullptr,
                                zA + BSN, zAblk + BSN);
  else              skinny_role(c2_16, W2t, (b - 256) * 16, smem, c2_32, 1.f, c4_32, nullptr,
                                nullptr, nullptr);
}

// E: W4t = NT(W2t,W2rm) (256) || x4 (128 -> traj[4], blk chain2) || x5 (128 -> traj[5], blk chain3)
__global__ __launch_bounds__(512, 4) void megaE(
    const bf16_t* __restrict__ W2t, const bf16_t* __restrict__ W2rm,
    const bf16_t* __restrict__ zA_in, const float* __restrict__ c2_32,
    bf16_t* __restrict__ W4t, float* __restrict__ traj4, float* __restrict__ traj5,
    bf16_t* __restrict__ zAblk) {
  __shared__ char smem[SMEM_BYTES];
  int b = blockIdx.x;
  if (b < 256)      wgemm_role(W2t, W2rm, W4t, nullptr, b, smem);
  else if (b < 384) skinny_role(zA_in, W2t, (b - 256) * 16, smem, c2_32, 1.f, traj4, nullptr,
                                nullptr, zAblk + 2 * BSN);
  else              skinny_role(zA_in + BSN, W2t, (b - 384) * 16, smem, c2_32, 1.f, traj5, nullptr,
                                nullptr, zAblk + 3 * BSN);
}

// ---------------------------------------------------------------------------
// quad_fused v4 (unchanged -- matched prediction): all 5 quad steps in one
// fence-free launch; blocked write-through hand-off; per-(step,chain)
// relaxed counters.
// ---------------------------------------------------------------------------
__global__ __launch_bounds__(512, 4) void quad_fused(
    const bf16_t* __restrict__ zblk_in, const bf16_t* __restrict__ W4t,
    const float* __restrict__ c4_32, float* __restrict__ traj6,
    bf16_t* __restrict__ zsteps, float* __restrict__ sfin, int* __restrict__ bar) {
  __shared__ char smem[SMEM_BYTES];
  int b = blockIdx.x, ci = b & 3, p = b >> 2;
  int tid = threadIdx.x, lane = tid & 63, wave = tid >> 6;
  int rl = lane & 15, q = lane >> 4;
  int n0 = p * 16;
  // stage W4t panel once (fragment order), reused for all 5 steps
#pragma unroll
  for (int i = 0; i < 8; ++i) {
    const bf16_t* g = W4t + (size_t)(n0 + rl) * NDIM + (i * 8 + wave) * 32 + q * 8;
    gload16(g, smem + (size_t)(i * 512 + wave * 64) * 16);
  }
  __syncthreads();

  int ms = (wave & 3) * 16, kh = wave >> 2;
  const bf16x8* Bp = (const bf16x8*)smem + lane + kh * 2048;
  f32x4*  red  = (f32x4*)(smem + 65536);   // 4 KB
  bf16_t* pack = (bf16_t*)(smem + 69632);  // 2 KB panel pack
  const bf16_t* zcur = zblk_in + (size_t)ci * BSN;
  // per-thread blocked A offset in bf16x8 units
  int aoff = (ms + rl) * 2 + (q & 1) + (q >> 1) * 128 + kh * 8192;

#pragma unroll 1
  for (int g = 0; g < 5; ++g) {
    const bf16x8* Az = (const bf16x8*)zcur + aoff;
    f32x4 acc[8];
#pragma unroll
    for (int i = 0; i < 8; ++i) acc[i] = (f32x4){0.f, 0.f, 0.f, 0.f};
#pragma unroll
    for (int c = 0; c < 32; ++c)
      acc[c & 7] = __builtin_amdgcn_mfma_f32_16x16x32_bf16(Az[c * 256], Bp[c * 64], acc[c & 7], 0, 0, 0);
    f32x4 s = ((acc[0] + acc[1]) + (acc[2] + acc[3])) + ((acc[4] + acc[5]) + (acc[6] + acc[7]));

    if (wave >= 4) red[(wave & 3) * 64 + lane] = s;
    __syncthreads();
    bf16_t* zn = zsteps + (size_t)g * ZSTRIDE + (size_t)ci * BSN;  // fresh blocked buffer
    if (wave < 4) {
      s += red[wave * 64 + lane];
      int mrow = ms + q * 4, col = n0 + rl;
      float* tj = traj6 + (size_t)(4 * g + ci) * BSN;
#pragma unroll
      for (int r = 0; r < 4; ++r) {
        size_t o = (size_t)(mrow + r) * NDIM + col;
        float v = c4_32[o] + s[r];
        tj[o] = v;
        if (g == 4 && ci == 3) sfin[o] = v;
        if (g < 4) pack[(mrow + r) * 16 + rl] = (bf16_t)v;
      }
    }
    if (g < 4) {
      __syncthreads();                     // panel pack complete in LDS
      if (tid < 128) {                     // coalesced 16B/lane agent stores
        int row = tid >> 1, hf = tid & 1;
        const u64_t* src = (const u64_t*)pack + row * 4 + hf * 2;
        u64_t* dst = (u64_t*)(zn + (size_t)p * 1024) + row * 4 + hf * 2;
        __hip_atomic_store(dst,     src[0], __ATOMIC_RELAXED, __HIP_MEMORY_SCOPE_AGENT);
        __hip_atomic_store(dst + 1, src[1], __ATOMIC_RELAXED, __HIP_MEMORY_SCOPE_AGENT);
      }
      __syncthreads();   // s_waitcnt vmcnt(0): all sc1 stores at coherence point
      if (tid == 0) {
        int* ctr = &bar[(g * 4 + ci) * 32];  // 128B-separated per (step,chain)
        __hip_atomic_fetch_add(ctr, 1, __ATOMIC_RELAXED, __HIP_MEMORY_SCOPE_AGENT);
        while (__hip_atomic_load(ctr, __ATOMIC_RELAXED, __HIP_MEMORY_SCOPE_AGENT) < 128)
          __builtin_amdgcn_s_sleep(1);
        asm volatile("" ::: "memory");     // no acquire fence: fresh buffer, no stale lines
      }
      __syncthreads();
      zcur = zn;
    }
  }
}

// ---------------------------------------------------------------------------
// Host driver: memset + 7 kernel nodes.
// ---------------------------------------------------------------------------
extern "C" void kernel_launch(void* const* d_in, const int* in_sizes, int n_in,
                              void* d_out, int out_size, void* d_ws, size_t ws_size,
                              hipStream_t stream) {
  const float* y    = (const float*)d_in[2];
  const float* H    = (const float*)d_in[3];
  const float* Dinv = (const float*)d_in[4];
  const float* U    = (const float*)d_in[5];
  const float* invM = (const float*)d_in[6];

  float* out     = (float*)d_out;
  float* s_final = out;
  float* traj    = out + BSN;

  char* ws = (char*)d_ws;
  size_t off = 0;
  auto alloc = [&](size_t bytes) -> void* {
    void* p = ws + off;
    off += (bytes + 255) & ~(size_t)255;
    return p;
  };
  bf16_t* U16   = (bf16_t*)alloc((size_t)NDIM * NDIM * 2);  // -> W2rm after megaA
  bf16_t* Dt16  = (bf16_t*)alloc((size_t)NDIM * NDIM * 2);  // -> W4t after megaB
  bf16_t* iMt16 = (bf16_t*)alloc((size_t)NDIM * NDIM * 2);
  bf16_t* H16   = (bf16_t*)alloc((size_t)NDIM * NDIM * 2);  // -> W2t after megaA
  bf16_t* Wrm   = (bf16_t*)alloc((size_t)NDIM * NDIM * 2);
  bf16_t* Wt    = (bf16_t*)alloc((size_t)NDIM * NDIM * 2);
  bf16_t* y16   = (bf16_t*)alloc(BSN * 2);
  bf16_t* yMF16 = (bf16_t*)alloc(BSN * 2);
  bf16_t* c16   = (bf16_t*)alloc(BSN * 2);
  bf16_t* c2_16 = (bf16_t*)alloc(BSN * 2);
  float*  c32   = (float*)alloc(BSN * 4);
  float*  c2_32 = (float*)alloc(BSN * 4);
  float*  c4_32 = (float*)alloc(BSN * 4);
  bf16_t* z0    = (bf16_t*)alloc(2 * BSN * 2);          // x0, x1 (row-major)
  bf16_t* zA    = (bf16_t*)alloc(2 * BSN * 2);          // x2, x3 row-major (megaE A-operand)
  bf16_t* zAblk = (bf16_t*)alloc(4 * BSN * 2);          // x2..x5 blocked (quad input)
  bf16_t* zsteps= (bf16_t*)alloc(5 * ZSTRIDE * 2);      // 5 fresh per-step blocked slabs
  int*    bar   = (int*)alloc(4096);                    // 16 per-(step,chain) counters
  bf16_t* W2t   = H16;   // H16 dead after megaA
  bf16_t* W2rm  = U16;   // U16 dead after megaA
  bf16_t* W4t   = Dt16;  // Dt16 dead after megaB

  hipMemsetAsync(bar, 0, 4096, stream);

  prep<<<3072, 512, 0, stream>>>(H, U, Dinv, invM, y, H16, U16, Dt16, iMt16, y16, traj);
  megaA<<<384, 512, 0, stream>>>(U16, iMt16, y16, H16, Wrm, Wt, yMF16);
  megaB<<<256, 512, 0, stream>>>(yMF16, iMt16, Dt16, c32, c16, z0);
  megaC<<<512, 512, 0, stream>>>(Wt, Wrm, z0, c16, c32, W2t, W2rm,
                                 traj + BSN, z0 + BSN, c2_32, c2_16);
  megaD<<<384, 512, 0, stream>>>(W2t, z0, c2_16, c2_32, traj + 2 * BSN, traj + 3 * BSN,
                                 zA, zAblk, c4_32);
  megaE<<<512, 512, 0, stream>>>(W2t, W2rm, zA, c2_32, W4t, traj + 4 * BSN, traj + 5 * BSN,
                                 zAblk);

  // all 5 quad steps in one fence-free launch: fresh blocked slab per step,
  // writes traj[6..25] + s_final
  quad_fused<<<512, 512, 0, stream>>>(zAblk, W4t, c4_32, traj + 6 * BSN,
                                      zsteps, s_final, bar);
}

// Round 14
// 255.722 us; speedup vs baseline: 1.1386x; 1.1047x over previous
//
#include <hip/hip_runtime.h>
#include <hip/hip_bf16.h>

#define NDIM 2048
#define BS   64
#define NM4  (NDIM * NDIM / 4)
#define BSN  ((size_t)BS * NDIM)
#define ZSTRIDE ((size_t)4 * BSN + 2048)   // 4-chain z slab + 4KB pad
#define SMEM_BYTES 71680    // mega kernels: 4x16KB pipeline (+34.8KB tileT); skinny 64+4+2KB
#define QSMEM_BYTES 143360  // quad: 2x64KB panel + 8KB red + 4KB pack (1 block/CU)

typedef __bf16 bf16_t;
typedef __bf16 bf16x4 __attribute__((ext_vector_type(4)));
typedef __bf16 bf16x8 __attribute__((ext_vector_type(8)));
typedef float  f32x4  __attribute__((ext_vector_type(4)));
typedef unsigned long long u64_t;

// Async global->LDS, 16 B per lane.  LDS dest = wave-uniform base + lane*16.
__device__ __forceinline__ void gload16(const void* g, void* lds) {
  __builtin_amdgcn_global_load_lds(
      (const __attribute__((address_space(1))) void*)g,
      (__attribute__((address_space(3))) void*)lds, 16, 0, 0);
}
// 32-bit LDS byte offset of a generic pointer into __shared__.
__device__ __forceinline__ uint32_t lds_off(void* p) {
  return (uint32_t)(uintptr_t)(__attribute__((address_space(3))) void*)p;
}

// ---------------------------------------------------------------------------
// prep (512 thr, 3072 blocks): b<1024 convert H,U (+y, traj0); else 64x64
// fp32->bf16 vectorized transposes of Dinv, invM.
// ---------------------------------------------------------------------------
__global__ __launch_bounds__(512) void prep(
    const float* __restrict__ H, const float* __restrict__ U,
    const float* __restrict__ Dinv, const float* __restrict__ invM,
    const float* __restrict__ y,
    bf16_t* __restrict__ H16, bf16_t* __restrict__ U16,
    bf16_t* __restrict__ Dt, bf16_t* __restrict__ iMt,
    bf16_t* __restrict__ y16, float* __restrict__ traj0) {
  __shared__ bf16_t tile[64][72];
  int b = blockIdx.x, tid = threadIdx.x;
  if (b < 1024) {
#pragma unroll
    for (int i = 0; i < 4; ++i) {
      int idx = b * 2048 + i * 512 + tid;
      const float* src = (idx < NM4) ? H : U;
      bf16_t* dst = (idx < NM4) ? H16 : U16;
      int j = (idx < NM4) ? idx : idx - NM4;
      float4 v = ((const float4*)src)[j];
      bf16x4 o = {(bf16_t)v.x, (bf16_t)v.y, (bf16_t)v.z, (bf16_t)v.w};
      ((bf16x4*)dst)[j] = o;
    }
    int yi = b * 512 + tid;
    if (yi < BS * NDIM / 4) {
      float4 w = ((const float4*)y)[yi];
      bf16x4 o2 = {(bf16_t)w.x, (bf16_t)w.y, (bf16_t)w.z, (bf16_t)w.w};
      ((bf16x4*)y16)[yi] = o2;
      ((float4*)traj0)[yi] = make_float4(0.f, 0.f, 0.f, 0.f);
    }
  } else {
    int id = b - 1024;
    const float* src = (id < 1024) ? Dinv : invM;
    bf16_t* dst = (id < 1024) ? Dt : iMt;
    id &= 1023;
    int bx = id & 31, by = id >> 5;
    int r = tid >> 3, c8 = (tid & 7) * 8;
    const float* sp = src + (size_t)(by * 64 + r) * NDIM + bx * 64 + c8;
    float4 v0 = *(const float4*)sp;
    float4 v1 = *(const float4*)(sp + 4);
    bf16_t* t = &tile[r][c8];
    t[0] = (bf16_t)v0.x; t[1] = (bf16_t)v0.y; t[2] = (bf16_t)v0.z; t[3] = (bf16_t)v0.w;
    t[4] = (bf16_t)v1.x; t[5] = (bf16_t)v1.y; t[6] = (bf16_t)v1.z; t[7] = (bf16_t)v1.w;
    __syncthreads();
    bf16x8 o;
#pragma unroll
    for (int j = 0; j < 8; ++j) o[j] = tile[c8 + j][r];
    *(bf16x8*)(dst + (size_t)(bx * 64 + r) * NDIM + by * 64 + c8) = o;
  }
}

// ---------------------------------------------------------------------------
// wgemm v11 (r13 VERBATIM -- 282.5us ship): reg-staged producer + XOR-swizzled
// conflict-free LDS, 128x128 tile, BK=32, pair-wise sync (32 barriers).
// ---------------------------------------------------------------------------
__device__ __forceinline__ void wgemm_role(
    const bf16_t* __restrict__ A, const bf16_t* __restrict__ Bt,
    bf16_t* __restrict__ C, bf16_t* __restrict__ Ct, int blk, char* smem) {
  int tid = threadIdx.x, lane = tid & 63, wave = tid >> 6;
  int xcd = blk & 7, jj = blk >> 3;
  int m0 = (((xcd >> 1) << 2) + (jj >> 3)) * 128;
  int n0 = (((xcd & 1) << 3) + (jj & 7)) * 128;
  int rl = lane & 15, q = lane >> 4;

  if (wave >= 4) {
    // ---- producer: coalesced reg loads, swizzled conflict-free ds_write ---
    int pw = wave - 4;
    int prow = lane >> 2, pkg = lane & 3;      // 4-lane 64B runs
    const bf16_t* PA0 = A  + (size_t)(m0 + pw * 32 + prow) * NDIM + pkg * 8;
    const bf16_t* PA1 = PA0 + 16 * NDIM;
    const bf16_t* PB0 = Bt + (size_t)(n0 + pw * 32 + prow) * NDIM + pkg * 8;
    const bf16_t* PB1 = PB0 + 16 * NDIM;
    char* WA = smem + pw * 2048 + (pkg * 256 + ((prow ^ (pkg * 2)) * 16));

    bf16x8 rE[4], rO[4];
#define PLOAD(R, s)                                  \
    {                                                \
      int _k = (s) * 32;                             \
      R[0] = *(const bf16x8*)(PA0 + _k);             \
      R[1] = *(const bf16x8*)(PA1 + _k);             \
      R[2] = *(const bf16x8*)(PB0 + _k);             \
      R[3] = *(const bf16x8*)(PB1 + _k);             \
    }
#define PWRITE(R, BUF)                               \
    {                                                \
      char* _w = WA + (BUF) * 16384;                 \
      *(bf16x8*)(_w)        = R[0];                  \
      *(bf16x8*)(_w + 1024) = R[1];                  \
      *(bf16x8*)(_w + 8192) = R[2];                  \
      *(bf16x8*)(_w + 9216) = R[3];                  \
    }
#define LB asm volatile("s_waitcnt lgkmcnt(0)\n\ts_barrier" ::: "memory")
    PLOAD(rE, 0); PLOAD(rO, 1);
    PWRITE(rE, 0); PLOAD(rE, 2);
    PWRITE(rO, 1); PLOAD(rO, 3);
    LB;                                    // #0: pair0 (bufs 0,1) ready
#pragma unroll 1
    for (int i = 1; i < 31; ++i) {
      int bb = (i & 1) * 2;
      PWRITE(rE, bb);     PLOAD(rE, 2 * i + 2);
      PWRITE(rO, bb + 1); PLOAD(rO, 2 * i + 3);
      LB;                                  // #i: pair i ready
    }
    PWRITE(rE, 2); PWRITE(rO, 3);          // pair 31 (chunks 62,63)
    LB;                                    // #31
#undef LB
#undef PWRITE
#undef PLOAD
    if (Ct) {
      __syncthreads();   // consumers writing tileT
      __syncthreads();
      bf16_t (*tileT)[136] = (bf16_t(*)[136])smem;
#pragma unroll
      for (int t = 0; t < 4; ++t) {
        int v = t * 512 + tid, row = v >> 4, c8 = (v & 15) * 8;
        *(bf16x8*)(Ct + (size_t)(n0 + row) * NDIM + m0 + c8) = *(bf16x8*)&tileT[row][c8];
      }
    }
    return;
  }

  // ------------------ consumer: 64x64 quadrant, 16 MFMA/chunk -------------
  int wr = wave & 1, wc = wave >> 1;
  uint32_t roff = (uint32_t)(q * 256 + ((rl ^ (q * 2)) * 16));   // swizzled frag
  uint32_t abase = lds_off(smem) + wr * 4096 + roff;
  uint32_t bbase = lds_off(smem) + 8192 + wc * 4096 + roff;

  f32x4 acc[4][4];
#pragma unroll
  for (int i = 0; i < 4; ++i)
#pragma unroll
    for (int j = 0; j < 4; ++j) acc[i][j] = (f32x4){0.f, 0.f, 0.f, 0.f};

#define CCOMPUTE(bb)                                                           \
  {                                                                            \
    uint32_t av = abase + (bb) * 16384;                                        \
    uint32_t bv = bbase + (bb) * 16384;                                        \
    bf16x8 a0, a1, a2, a3, b0, b1, b2, b3;                                     \
    asm volatile("ds_read_b128 %0, %1"             : "=v"(a0) : "v"(av));      \
    asm volatile("ds_read_b128 %0, %1 offset:1024" : "=v"(a1) : "v"(av));      \
    asm volatile("ds_read_b128 %0, %1 offset:2048" : "=v"(a2) : "v"(av));      \
    asm volatile("ds_read_b128 %0, %1 offset:3072" : "=v"(a3) : "v"(av));      \
    asm volatile("ds_read_b128 %0, %1"             : "=v"(b0) : "v"(bv));      \
    asm volatile("ds_read_b128 %0, %1 offset:1024" : "=v"(b1) : "v"(bv));      \
    asm volatile("ds_read_b128 %0, %1 offset:2048" : "=v"(b2) : "v"(bv));      \
    asm volatile("ds_read_b128 %0, %1 offset:3072" : "=v"(b3) : "v"(bv));      \
    asm volatile("s_waitcnt lgkmcnt(0)"                                        \
                 : "+v"(a0), "+v"(a1), "+v"(a2), "+v"(a3), "+v"(b0),           \
                   "+v"(b1), "+v"(b2), "+v"(b3));                              \
    acc[0][0] = __builtin_amdgcn_mfma_f32_16x16x32_bf16(a0, b0, acc[0][0], 0, 0, 0); \
    acc[0][1] = __builtin_amdgcn_mfma_f32_16x16x32_bf16(a0, b1, acc[0][1], 0, 0, 0); \
    acc[0][2] = __builtin_amdgcn_mfma_f32_16x16x32_bf16(a0, b2, acc[0][2], 0, 0, 0); \
    acc[0][3] = __builtin_amdgcn_mfma_f32_16x16x32_bf16(a0, b3, acc[0][3], 0, 0, 0); \
    acc[1][0] = __builtin_amdgcn_mfma_f32_16x16x32_bf16(a1, b0, acc[1][0], 0, 0, 0); \
    acc[1][1] = __builtin_amdgcn_mfma_f32_16x16x32_bf16(a1, b1, acc[1][1], 0, 0, 0); \
    acc[1][2] = __builtin_amdgcn_mfma_f32_16x16x32_bf16(a1, b2, acc[1][2], 0, 0, 0); \
    acc[1][3] = __builtin_amdgcn_mfma_f32_16x16x32_bf16(a1, b3, acc[1][3], 0, 0, 0); \
    acc[2][0] = __builtin_amdgcn_mfma_f32_16x16x32_bf16(a2, b0, acc[2][0], 0, 0, 0); \
    acc[2][1] = __builtin_amdgcn_mfma_f32_16x16x32_bf16(a2, b1, acc[2][1], 0, 0, 0); \
    acc[2][2] = __builtin_amdgcn_mfma_f32_16x16x32_bf16(a2, b2, acc[2][2], 0, 0, 0); \
    acc[2][3] = __builtin_amdgcn_mfma_f32_16x16x32_bf16(a2, b3, acc[2][3], 0, 0, 0); \
    acc[3][0] = __builtin_amdgcn_mfma_f32_16x16x32_bf16(a3, b0, acc[3][0], 0, 0, 0); \
    acc[3][1] = __builtin_amdgcn_mfma_f32_16x16x32_bf16(a3, b1, acc[3][1], 0, 0, 0); \
    acc[3][2] = __builtin_amdgcn_mfma_f32_16x16x32_bf16(a3, b2, acc[3][2], 0, 0, 0); \
    acc[3][3] = __builtin_amdgcn_mfma_f32_16x16x32_bf16(a3, b3, acc[3][3], 0, 0, 0); \
  }

#pragma unroll 1
  for (int k = 0; k < 32; ++k) {
    int bb = (k & 1) * 2;
    asm volatile("s_barrier" ::: "memory");
    CCOMPUTE(bb);
    CCOMPUTE(bb + 1);
  }
#undef CCOMPUTE

  // normal-orientation store (C[m][n]); C/D layout: col=lane&15, row=q*4+reg
#pragma unroll
  for (int i = 0; i < 4; ++i)
#pragma unroll
    for (int j = 0; j < 4; ++j)
#pragma unroll
      for (int r = 0; r < 4; ++r)
        C[(size_t)(m0 + wr * 64 + i * 16 + q * 4 + r) * NDIM + n0 + wc * 64 + j * 16 + rl] =
            (bf16_t)acc[i][j][r];

  // optional transposed store (Ct[n][m]) via LDS round-trip
  if (Ct) {
    __syncthreads();
    bf16_t (*tileT)[136] = (bf16_t(*)[136])smem;   // 128 x 136 x 2 B = 34.8 KB
#pragma unroll
    for (int i = 0; i < 4; ++i)
#pragma unroll
      for (int j = 0; j < 4; ++j)
#pragma unroll
        for (int r = 0; r < 4; ++r)
          tileT[wc * 64 + j * 16 + rl][wr * 64 + i * 16 + q * 4 + r] = (bf16_t)acc[i][j][r];
    __syncthreads();
#pragma unroll
    for (int t = 0; t < 4; ++t) {
      int v = t * 512 + tid, row = v >> 4, c8 = (v & 15) * 8;
      *(bf16x8*)(Ct + (size_t)(n0 + row) * NDIM + m0 + c8) = *(bf16x8*)&tileT[row][c8];
    }
  }
}

// ---------------------------------------------------------------------------
// skinny v4 (r13 form): C[64,16] = add + sign*(A[64,2048] @ Bt^T cols n0..+15).
// ---------------------------------------------------------------------------
__device__ __forceinline__ void skinny_role(
    const bf16_t* __restrict__ A, const bf16_t* __restrict__ Bt, int n0, char* smem,
    const float* __restrict__ add, float sign,
    float* o32, float* o32b, bf16_t* o16, bf16_t* o16blk) {
  int tid = threadIdx.x, lane = tid & 63, wave = tid >> 6;
  int rl = lane & 15, q = lane >> 4;
#pragma unroll
  for (int i = 0; i < 8; ++i) {
    const bf16_t* g = Bt + (size_t)(n0 + rl) * NDIM + (i * 8 + wave) * 32 + q * 8;
    gload16(g, smem + (size_t)(i * 512 + wave * 64) * 16);
  }
  __syncthreads();

  int ms = (wave & 3) * 16, kh = wave >> 2;
  const bf16x8* Ap = (const bf16x8*)(A + (size_t)(ms + rl) * NDIM) + q + kh * 128;
  const bf16x8* Bp = (const bf16x8*)smem + lane + kh * 2048;

  f32x4 acc[8];
#pragma unroll
  for (int i = 0; i < 8; ++i) acc[i] = (f32x4){0.f, 0.f, 0.f, 0.f};
#pragma unroll
  for (int c = 0; c < 32; ++c)
    acc[c & 7] = __builtin_amdgcn_mfma_f32_16x16x32_bf16(Ap[c * 4], Bp[c * 64], acc[c & 7], 0, 0, 0);
  f32x4 s = ((acc[0] + acc[1]) + (acc[2] + acc[3])) + ((acc[4] + acc[5]) + (acc[6] + acc[7]));

  f32x4* red = (f32x4*)(smem + 65536);
  if (wave >= 4) red[(wave & 3) * 64 + lane] = s;
  __syncthreads();
  if (wave < 4) {
    s += red[wave * 64 + lane];
    int mrow = ms + q * 4, col = n0 + rl;
#pragma unroll
    for (int r = 0; r < 4; ++r) {
      size_t o = (size_t)(mrow + r) * NDIM + col;
      float v = sign * s[r];
      if (add) v += add[o];
      if (o32)  o32[o]  = v;
      if (o32b) o32b[o] = v;
      if (o16)  o16[o]  = (bf16_t)v;
      if (o16blk) o16blk[(size_t)(n0 >> 4) * 1024 + (mrow + r) * 16 + rl] = (bf16_t)v;
    }
  }
}

// --------------------------- mega nodes (512 thr) --------------------------
// A: W = U@invM, dual store Wrm+Wt (256 wgemm) || yMF = y@H^T (128 skinny)
__global__ __launch_bounds__(512, 4) void megaA(
    const bf16_t* __restrict__ U16, const bf16_t* __restrict__ iMt16,
    const bf16_t* __restrict__ y16, const bf16_t* __restrict__ H16,
    bf16_t* __restrict__ Wrm, bf16_t* __restrict__ Wt, bf16_t* __restrict__ yMF16) {
  __shared__ char smem[SMEM_BYTES];
  int b = blockIdx.x;
  if (b < 256) wgemm_role(U16, iMt16, Wrm, Wt, b, smem);
  else         skinny_role(y16, H16, (b - 256) * 16, smem, nullptr, 1.f,
                           nullptr, nullptr, yMF16, nullptr);
}

// B (light): c = yMF@invM (128) || x0 = yMF@Dinv (128 -> z0)
__global__ __launch_bounds__(512, 4) void megaB(
    const bf16_t* __restrict__ yMF16, const bf16_t* __restrict__ iMt16,
    const bf16_t* __restrict__ Dt16,
    float* __restrict__ c32, bf16_t* __restrict__ c16, bf16_t* __restrict__ z0) {
  __shared__ char smem[SMEM_BYTES];
  int b = blockIdx.x;
  if (b < 128) skinny_role(yMF16, iMt16, b * 16, smem, nullptr, 1.f, c32, nullptr, c16, nullptr);
  else         skinny_role(yMF16, Dt16, (b - 128) * 16, smem, nullptr, 1.f, nullptr, nullptr, z0, nullptr);
}

// C: W2 = NT(Wt,Wrm), dual store W2t+W2rm (256) || x1 (128 -> traj[1], z0+BSN)
//    || c2 (128)
__global__ __launch_bounds__(512, 4) void megaC(
    const bf16_t* __restrict__ Wt, const bf16_t* __restrict__ Wrm,
    const bf16_t* __restrict__ z0, const bf16_t* __restrict__ c16,
    const float* __restrict__ c32,
    bf16_t* __restrict__ W2t, bf16_t* __restrict__ W2rm,
    float* __restrict__ traj1, bf16_t* __restrict__ z0b,
    float* __restrict__ c2_32, bf16_t* __restrict__ c2_16) {
  __shared__ char smem[SMEM_BYTES];
  int b = blockIdx.x;
  if (b < 256)      wgemm_role(Wt, Wrm, W2t, W2rm, b, smem);
  else if (b < 384) skinny_role(z0, Wt, (b - 256) * 16, smem, c32, -1.f, traj1, nullptr, z0b, nullptr);
  else              skinny_role(c16, Wt, (b - 384) * 16, smem, c32, -1.f, c2_32, nullptr, c2_16, nullptr);
}

// D (light): x2 (128 -> traj[2], zA row + blk) || x3 (128 -> traj[3]) || c4 (128)
__global__ __launch_bounds__(512, 4) void megaD(
    const bf16_t* __restrict__ W2t, const bf16_t* __restrict__ z0,
    const bf16_t* __restrict__ c2_16, const float* __restrict__ c2_32,
    float* __restrict__ traj2, float* __restrict__ traj3,
    bf16_t* __restrict__ zA, bf16_t* __restrict__ zAblk, float* __restrict__ c4_32) {
  __shared__ char smem[SMEM_BYTES];
  int b = blockIdx.x;
  if (b < 128)      skinny_role(z0, W2t, b * 16, smem, c2_32, 1.f, traj2, nullptr, zA, zAblk);
  else if (b < 256) skinny_role(z0 + BSN, W2t, (b - 128) * 16, smem, c2_32, 1.f, traj3, nullptr,
                                zA + BSN, zAblk + BSN);
  else              skinny_role(c2_16, W2t, (b - 256) * 16, smem, c2_32, 1.f, c4_32, nullptr,
                                nullptr, nullptr);
}

// E: W4t = NT(W2t,W2rm) (256) || x4 (128 -> traj[4], blk chain2) || x5 (128 -> traj[5], blk chain3)
__global__ __launch_bounds__(512, 4) void megaE(
    const bf16_t* __restrict__ W2t, const bf16_t* __restrict__ W2rm,
    const bf16_t* __restrict__ zA_in, const float* __restrict__ c2_32,
    bf16_t* __restrict__ W4t, float* __restrict__ traj4, float* __restrict__ traj5,
    bf16_t* __restrict__ zAblk) {
  __shared__ char smem[SMEM_BYTES];
  int b = blockIdx.x;
  if (b < 256)      wgemm_role(W2t, W2rm, W4t, nullptr, b, smem);
  else if (b < 384) skinny_role(zA_in, W2t, (b - 256) * 16, smem, c2_32, 1.f, traj4, nullptr,
                                nullptr, zAblk + 2 * BSN);
  else              skinny_role(zA_in + BSN, W2t, (b - 384) * 16, smem, c2_32, 1.f, traj5, nullptr,
                                nullptr, zAblk + 3 * BSN);
}

// ---------------------------------------------------------------------------
// quad_fused v5 (32-col panels, 256 blocks): all 5 quad steps in one
// fence-free launch.  r13 analysis: 512 blocks each re-read the full 256KB
// chain-z per step -> 128MB/step L2 traffic + 128 arrivals/chain barrier.
// v5 doubles the per-block panel to 32 cols (two blocked 16-panels 2p,2p+1,
// each staged/consumed exactly like v4): 256 blocks (1/CU at 140KB LDS, all
// resident), 64MB/step z traffic, 64 arrivals/chain, and each z fragment
// load feeds TWO MFMAs.  Hand-off layout + protocol unchanged.
// ---------------------------------------------------------------------------
__global__ __launch_bounds__(512, 2) void quad_fused(
    const bf16_t* __restrict__ zblk_in, const bf16_t* __restrict__ W4t,
    const float* __restrict__ c4_32, float* __restrict__ traj6,
    bf16_t* __restrict__ zsteps, float* __restrict__ sfin, int* __restrict__ bar) {
  __shared__ char smem[QSMEM_BYTES];
  int b = blockIdx.x, ci = b & 3, p = b >> 2;         // p in [0,64)
  int tid = threadIdx.x, lane = tid & 63, wave = tid >> 6;
  int rl = lane & 15, q = lane >> 4;
  int n0 = p * 32;
  // stage BOTH 16-col W4t sub-panels once (fragment order each)
#pragma unroll
  for (int s = 0; s < 2; ++s)
#pragma unroll
    for (int i = 0; i < 8; ++i) {
      const bf16_t* g = W4t + (size_t)(n0 + s * 16 + rl) * NDIM + (i * 8 + wave) * 32 + q * 8;
      gload16(g, smem + s * 65536 + (size_t)(i * 512 + wave * 64) * 16);
    }
  __syncthreads();

  int ms = (wave & 3) * 16, kh = wave >> 2;
  const bf16x8* Bp0 = (const bf16x8*)smem + lane + kh * 2048;
  const bf16x8* Bp1 = (const bf16x8*)(smem + 65536) + lane + kh * 2048;
  f32x4*  red0 = (f32x4*)(smem + 131072);   // 4 KB
  f32x4*  red1 = (f32x4*)(smem + 135168);   // 4 KB
  bf16_t* pack = (bf16_t*)(smem + 139264);  // 4 KB (two 2KB sub-panels)
  const bf16_t* zcur = zblk_in + (size_t)ci * BSN;
  // per-thread blocked A offset in bf16x8 units (unchanged layout)
  int aoff = (ms + rl) * 2 + (q & 1) + (q >> 1) * 128 + kh * 8192;

#pragma unroll 1
  for (int g = 0; g < 5; ++g) {
    const bf16x8* Az = (const bf16x8*)zcur + aoff;
    f32x4 ac0[8], ac1[8];
#pragma unroll
    for (int i = 0; i < 8; ++i) { ac0[i] = (f32x4){0.f, 0.f, 0.f, 0.f};
                                  ac1[i] = (f32x4){0.f, 0.f, 0.f, 0.f}; }
#pragma unroll
    for (int c = 0; c < 32; ++c) {
      bf16x8 af = Az[c * 256];                      // shared A fragment
      ac0[c & 7] = __builtin_amdgcn_mfma_f32_16x16x32_bf16(af, Bp0[c * 64], ac0[c & 7], 0, 0, 0);
      ac1[c & 7] = __builtin_amdgcn_mfma_f32_16x16x32_bf16(af, Bp1[c * 64], ac1[c & 7], 0, 0, 0);
    }
    f32x4 s0 = ((ac0[0] + ac0[1]) + (ac0[2] + ac0[3])) + ((ac0[4] + ac0[5]) + (ac0[6] + ac0[7]));
    f32x4 s1 = ((ac1[0] + ac1[1]) + (ac1[2] + ac1[3])) + ((ac1[4] + ac1[5]) + (ac1[6] + ac1[7]));

    if (wave >= 4) { red0[(wave & 3) * 64 + lane] = s0; red1[(wave & 3) * 64 + lane] = s1; }
    __syncthreads();
    bf16_t* zn = zsteps + (size_t)g * ZSTRIDE + (size_t)ci * BSN;  // fresh blocked buffer
    if (wave < 4) {
      s0 += red0[wave * 64 + lane];
      s1 += red1[wave * 64 + lane];
      int mrow = ms + q * 4;
      float* tj = traj6 + (size_t)(4 * g + ci) * BSN;
#pragma unroll
      for (int r = 0; r < 4; ++r) {
        size_t o0 = (size_t)(mrow + r) * NDIM + n0 + rl;
        size_t o1 = o0 + 16;
        float v0 = c4_32[o0] + s0[r];
        float v1 = c4_32[o1] + s1[r];
        tj[o0] = v0; tj[o1] = v1;
        if (g == 4 && ci == 3) { sfin[o0] = v0; sfin[o1] = v1; }
        if (g < 4) {
          pack[(mrow + r) * 16 + rl]        = (bf16_t)v0;
          pack[1024 + (mrow + r) * 16 + rl] = (bf16_t)v1;
        }
      }
    }
    if (g < 4) {
      __syncthreads();                     // panel pack complete in LDS
      if (tid < 256) {                     // coalesced 16B/lane agent stores, 2 sub-panels
        int s = tid >> 7, t2 = tid & 127;
        int row = t2 >> 1, hf = t2 & 1;
        const u64_t* src = (const u64_t*)pack + s * 256 + row * 4 + hf * 2;
        u64_t* dst = (u64_t*)(zn + (size_t)(2 * p + s) * 1024) + row * 4 + hf * 2;
        __hip_atomic_store(dst,     src[0], __ATOMIC_RELAXED, __HIP_MEMORY_SCOPE_AGENT);
        __hip_atomic_store(dst + 1, src[1], __ATOMIC_RELAXED, __HIP_MEMORY_SCOPE_AGENT);
      }
      __syncthreads();   // s_waitcnt vmcnt(0): all sc1 stores at coherence point
      if (tid == 0) {
        int* ctr = &bar[(g * 4 + ci) * 32];  // 128B-separated per (step,chain)
        __hip_atomic_fetch_add(ctr, 1, __ATOMIC_RELAXED, __HIP_MEMORY_SCOPE_AGENT);
        while (__hip_atomic_load(ctr, __ATOMIC_RELAXED, __HIP_MEMORY_SCOPE_AGENT) < 64)
          __builtin_amdgcn_s_sleep(1);
        asm volatile("" ::: "memory");     // no acquire fence: fresh buffer, no stale lines
      }
      __syncthreads();
      zcur = zn;
    }
  }
}

// ---------------------------------------------------------------------------
// Host driver: memset + 7 kernel nodes.
// ---------------------------------------------------------------------------
extern "C" void kernel_launch(void* const* d_in, const int* in_sizes, int n_in,
                              void* d_out, int out_size, void* d_ws, size_t ws_size,
                              hipStream_t stream) {
  const float* y    = (const float*)d_in[2];
  const float* H    = (const float*)d_in[3];
  const float* Dinv = (const float*)d_in[4];
  const float* U    = (const float*)d_in[5];
  const float* invM = (const float*)d_in[6];

  float* out     = (float*)d_out;
  float* s_final = out;
  float* traj    = out + BSN;

  char* ws = (char*)d_ws;
  size_t off = 0;
  auto alloc = [&](size_t bytes) -> void* {
    void* p = ws + off;
    off += (bytes + 255) & ~(size_t)255;
    return p;
  };
  bf16_t* U16   = (bf16_t*)alloc((size_t)NDIM * NDIM * 2);  // -> W2rm after megaA
  bf16_t* Dt16  = (bf16_t*)alloc((size_t)NDIM * NDIM * 2);  // -> W4t after megaB
  bf16_t* iMt16 = (bf16_t*)alloc((size_t)NDIM * NDIM * 2);
  bf16_t* H16   = (bf16_t*)alloc((size_t)NDIM * NDIM * 2);  // -> W2t after megaA
  bf16_t* Wrm   = (bf16_t*)alloc((size_t)NDIM * NDIM * 2);
  bf16_t* Wt    = (bf16_t*)alloc((size_t)NDIM * NDIM * 2);
  bf16_t* y16   = (bf16_t*)alloc(BSN * 2);
  bf16_t* yMF16 = (bf16_t*)alloc(BSN * 2);
  bf16_t* c16   = (bf16_t*)alloc(BSN * 2);
  bf16_t* c2_16 = (bf16_t*)alloc(BSN * 2);
  float*  c32   = (float*)alloc(BSN * 4);
  float*  c2_32 = (float*)alloc(BSN * 4);
  float*  c4_32 = (float*)alloc(BSN * 4);
  bf16_t* z0    = (bf16_t*)alloc(2 * BSN * 2);          // x0, x1 (row-major)
  bf16_t* zA    = (bf16_t*)alloc(2 * BSN * 2);          // x2, x3 row-major (megaE A-operand)
  bf16_t* zAblk = (bf16_t*)alloc(4 * BSN * 2);          // x2..x5 blocked (quad input)
  bf16_t* zsteps= (bf16_t*)alloc(5 * ZSTRIDE * 2);      // 5 fresh per-step blocked slabs
  int*    bar   = (int*)alloc(4096);                    // 16 per-(step,chain) counters
  bf16_t* W2t   = H16;   // H16 dead after megaA
  bf16_t* W2rm  = U16;   // U16 dead after megaA
  bf16_t* W4t   = Dt16;  // Dt16 dead after megaB

  hipMemsetAsync(bar, 0, 4096, stream);

  prep<<<3072, 512, 0, stream>>>(H, U, Dinv, invM, y, H16, U16, Dt16, iMt16, y16, traj);
  megaA<<<384, 512, 0, stream>>>(U16, iMt16, y16, H16, Wrm, Wt, yMF16);
  megaB<<<256, 512, 0, stream>>>(yMF16, iMt16, Dt16, c32, c16, z0);
  megaC<<<512, 512, 0, stream>>>(Wt, Wrm, z0, c16, c32, W2t, W2rm,
                                 traj + BSN, z0 + BSN, c2_32, c2_16);
  megaD<<<384, 512, 0, stream>>>(W2t, z0, c2_16, c2_32, traj + 2 * BSN, traj + 3 * BSN,
                                 zA, zAblk, c4_32);
  megaE<<<512, 512, 0, stream>>>(W2t, W2rm, zA, c2_32, W4t, traj + 4 * BSN, traj + 5 * BSN,
                                 zAblk);

  // all 5 quad steps in one fence-free launch (256 blocks, 32-col panels):
  // fresh blocked slab per step, writes traj[6..25] + s_final
  quad_fused<<<256, 512, 0, stream>>>(zAblk, W4t, c4_32, traj + 6 * BSN,
                                      zsteps, s_final, bar);
}